// Round 8
// baseline (847.842 us; speedup 1.0000x reference)
//
#include <hip/hip_runtime.h>
#include <hip/hip_bf16.h>

// Spiking attention, N=C=2048, T=10, heads=16, head_dim=128.
//
// Accuracy: spike decisions match an fp64 pipeline. Bulk GEMMs are bf16x2
// RNE-split MFMA (3 passes a1b1+a1b2+a2b1; sigma_dy ~ 3.5e-6). Closed-form IF
// epilogue certifies each channel (FLAG_EPS=4e-4 >= 11 sigma of 10x-amplified
// dy) or flags it; flagged channels recomputed exactly in fp64 (rescue).
// Constant input => IF spike train periodic, period J = first spike step;
// masks stored as J (u8); mask = LUT[J].
//
// R8 changes vs R7 (numerics untouched):
//  - gemm_dma: supertile XCD swizzle (8bx x 8by per 64 flat ids, sx=id&7) so
//    each XCD's concurrent blocks share one B image -> B stays L2-resident;
//    kills the LLC->L2 path saturation (the R6/R7 477us flatline).
//  - gemm_dma: back to single 32 KB LDS buffer (R6==R7 proved dbuf neutral;
//    smaller LDS -> 3 blocks/CU possible).
//
// ws layout (111.2 MB):
//   @0        MaskJ u8 25.17 MB   | after spike_attn: WOpk 16.78 MB
//   @25.17M   Bpk 50.33 MB        | after gemm<0>: WT f32 50.33
//                                 | after rescue: Xbpk 16.78
//   @75.50M   Apk 33.55 MB        | after gemm<0>: xbar f32 16.78
//   @109.05M  list u32 512K = 2 MB, then cnt u32

#define LIST_CAP (512u * 1024u)
#define FLAG_EPS 4e-4f

typedef __attribute__((ext_vector_type(8))) short short8;
typedef __attribute__((ext_vector_type(4))) float floatx4;

__device__ const unsigned d_LUT[16] = {0u, 0x3FFu, 0x2AAu, 0x124u, 0x88u,
                                       0x210u, 0x20u, 0x40u, 0x80u, 0x100u,
                                       0x200u, 0u, 0u, 0u, 0u, 0u};

// RNE split f32 -> two bf16 planes (raw u16 in low half).
__device__ __forceinline__ void bf16x2_rne(float a, unsigned& p1, unsigned& p2) {
  const unsigned u = __float_as_uint(a);
  const unsigned t1 = u + 0x7FFFu + ((u >> 16) & 1u);
  p1 = t1 >> 16;
  const float r = a - __uint_as_float(t1 & 0xFFFF0000u);
  const unsigned u2 = __float_as_uint(r);
  p2 = (u2 + 0x7FFFu + ((u2 >> 16) & 1u)) >> 16;
}

// ---- wsplit: W columns -> packed swizzled plane-tile images (image row =
// W column). Image (plane,ct,k0i): row r at r*32 shorts, chunk c (8 shorts)
// at 8*(c ^ ((r>>1)&3)).
template <int ZERO_CNT>
__global__ __launch_bounds__(256) void wsplit(
    const float* __restrict__ W0, const float* __restrict__ W1,
    const float* __restrict__ W2, unsigned short* __restrict__ Bpk,
    int NCT, unsigned* __restrict__ cnt) {
  if (ZERO_CNT && blockIdx.x == 0 && blockIdx.y == 0 && threadIdx.x == 0)
    *cnt = 0u;
  __shared__ float Wf[32 * 132];
  const int ct = blockIdx.x, k0 = blockIdx.y * 32;
  const int c0 = ct * 128;
  const int sel = c0 >> 11;
  const float* W = (sel == 0) ? W0 : ((sel == 1) ? W1 : W2);
  const int cc0 = c0 & 2047;
  const int t = threadIdx.x;

  const int kr = t >> 3, cq = (t & 7) * 16;
#pragma unroll
  for (int u = 0; u < 4; u++) {
    const float4 v = *(const float4*)(W + (size_t)(k0 + kr) * 2048 + cc0 + cq + 4 * u);
    *(float4*)&Wf[kr * 132 + cq + 4 * u] = v;
  }
  __syncthreads();

  const int cc = t >> 1, ch0 = (t & 1) * 2;
  unsigned short* img1 = Bpk + ((size_t)(0 * NCT + ct) * 64 + blockIdx.y) * 4096;
  unsigned short* img2 = Bpk + ((size_t)(1 * NCT + ct) * 64 + blockIdx.y) * 4096;
#pragma unroll
  for (int c = ch0; c < ch0 + 2; c++) {
    unsigned q1[8], q2[8];
#pragma unroll
    for (int e = 0; e < 8; e++) bf16x2_rne(Wf[(c * 8 + e) * 132 + cc], q1[e], q2[e]);
    const int off = cc * 32 + 8 * (c ^ ((cc >> 1) & 3));
    uint4 P1, P2;
    P1.x = q1[0] | (q1[1] << 16); P1.y = q1[2] | (q1[3] << 16);
    P1.z = q1[4] | (q1[5] << 16); P1.w = q1[6] | (q1[7] << 16);
    P2.x = q2[0] | (q2[1] << 16); P2.y = q2[2] | (q2[3] << 16);
    P2.z = q2[4] | (q2[5] << 16); P2.w = q2[6] | (q2[7] << 16);
    *(uint4*)&img1[off] = P1;
    *(uint4*)&img2[off] = P2;
  }
}

// ---- asplit: row-major A (optionally relu(+-)) -> packed swizzled images.
template <int RELU>
__global__ __launch_bounds__(256) void asplit(
    const float* __restrict__ src, unsigned short* __restrict__ Apk, int NRT) {
  const int rt = blockIdx.x, k0i = blockIdx.y;
  const int t = threadIdx.x;
  const int r = t >> 1, half = t & 1;
  int grow = rt * 128 + r;
  float sgn = 1.f;
  if (RELU && grow >= 2048) { grow -= 2048; sgn = -1.f; }
  const float* s = src + (size_t)grow * 2048 + k0i * 32 + half * 16;
  float f[16];
#pragma unroll
  for (int u = 0; u < 4; u++) {
    const float4 v = *(const float4*)(s + 4 * u);
    f[4 * u + 0] = v.x; f[4 * u + 1] = v.y;
    f[4 * u + 2] = v.z; f[4 * u + 3] = v.w;
  }
  if (RELU) {
#pragma unroll
    for (int e = 0; e < 16; e++) f[e] = fmaxf(sgn * f[e], 0.f);
  }
  unsigned q1[16], q2[16];
#pragma unroll
  for (int e = 0; e < 16; e++) bf16x2_rne(f[e], q1[e], q2[e]);

  unsigned short* img1 = Apk + ((size_t)(0 * NRT + rt) * 64 + k0i) * 4096;
  unsigned short* img2 = Apk + ((size_t)(1 * NRT + rt) * 64 + k0i) * 4096;
#pragma unroll
  for (int cc = 0; cc < 2; cc++) {
    const int c = half * 2 + cc;
    const int off = r * 32 + 8 * (c ^ ((r >> 1) & 3));
    const int e0 = cc * 8;
    uint4 P1, P2;
    P1.x = q1[e0 + 0] | (q1[e0 + 1] << 16); P1.y = q1[e0 + 2] | (q1[e0 + 3] << 16);
    P1.z = q1[e0 + 4] | (q1[e0 + 5] << 16); P1.w = q1[e0 + 6] | (q1[e0 + 7] << 16);
    P2.x = q2[e0 + 0] | (q2[e0 + 1] << 16); P2.y = q2[e0 + 2] | (q2[e0 + 3] << 16);
    P2.z = q2[e0 + 4] | (q2[e0 + 5] << 16); P2.w = q2[e0 + 6] | (q2[e0 + 7] << 16);
    *(uint4*)&img1[off] = P1;
    *(uint4*)&img2[off] = P2;
  }
}

// ---- gemm_dma: pure-DMA bf16x2 MFMA GEMM, 128x128 tile, BK=32, 2x2 waves,
// single 32 KB buffer, flat grid + supertile XCD swizzle:
// id -> supertile st = id>>6 (8bx x 8by); sx = id&7 (-> bx), sy = (id>>3)&7.
// With round-robin XCD = id%8, each XCD's ids in a supertile share one bx
// -> the B image (1 MB) stays L2-resident on that XCD.
// MODE 0: closed-form IF -> MaskJ u8 + certify/flag. MODE 1: store y*0.1.
template <int MODE>
__global__ __launch_bounds__(256) void gemm_dma(
    const unsigned short* __restrict__ Apk, const unsigned short* __restrict__ Bpk,
    int NRT, int NCT, int SX, unsigned char* __restrict__ MaskJ,
    unsigned* __restrict__ list, unsigned* __restrict__ cnt,
    float* __restrict__ Out) {
  __shared__ unsigned short sh[4][4096];  // A p1, A p2, B p1, B p2
  __shared__ unsigned lutS[16];

  const int tid = threadIdx.x;
  const int id = blockIdx.x;
  const int st = id >> 6, w = id & 63;
  const int bx = (st % SX) * 8 + (w & 7);
  const int by = (st / SX) * 8 + ((w >> 3) & 7);

  const int lane = tid & 63, wave = tid >> 6;
  const int wr = wave >> 1, wc = wave & 1;
  const int lm = lane & 15, lg = lane >> 4;

  if (MODE == 0 && tid < 16) lutS[tid] = d_LUT[tid];

  // each wave DMAs one 8 KB image per k-step
  const unsigned short* gsrc =
      (wave < 2) ? (Apk + ((size_t)(wave * NRT + by) * 64) * 4096)
                 : (Bpk + ((size_t)((wave - 2) * NCT + bx) * 64) * 4096);

  floatx4 acc[4][4];
#pragma unroll
  for (int i = 0; i < 4; i++)
#pragma unroll
    for (int j = 0; j < 4; j++) acc[i][j] = (floatx4){0.f, 0.f, 0.f, 0.f};

  for (int k0i = 0; k0i < 64; k0i++) {
    __syncthreads();  // prior iteration's fragment reads complete
    const unsigned short* gp = gsrc + (size_t)k0i * 4096;
#pragma unroll
    for (int i = 0; i < 8; i++) {
      __builtin_amdgcn_global_load_lds(
          (const __attribute__((address_space(1))) unsigned*)(gp + i * 512 + lane * 8),
          (__attribute__((address_space(3))) unsigned*)(&sh[wave][i * 512]), 16, 0, 0);
    }
    __syncthreads();  // drains vmcnt -> DMA landed

    short8 a1[4], a2[4], b1[4], b2[4];
#pragma unroll
    for (int i = 0; i < 4; i++) {
      const int row = 64 * wr + 16 * i + lm;
      const int off = row * 32 + 8 * (lg ^ ((row >> 1) & 3));
      a1[i] = *(const short8*)&sh[0][off];
      a2[i] = *(const short8*)&sh[1][off];
    }
#pragma unroll
    for (int j = 0; j < 4; j++) {
      const int row = 64 * wc + 16 * j + lm;
      const int off = row * 32 + 8 * (lg ^ ((row >> 1) & 3));
      b1[j] = *(const short8*)&sh[2][off];
      b2[j] = *(const short8*)&sh[3][off];
    }
#pragma unroll
    for (int i = 0; i < 4; i++)
#pragma unroll
      for (int j = 0; j < 4; j++)
        acc[i][j] = __builtin_amdgcn_mfma_f32_16x16x32_bf16(a1[i], b1[j], acc[i][j], 0, 0, 0);
#pragma unroll
    for (int i = 0; i < 4; i++)
#pragma unroll
      for (int j = 0; j < 4; j++)
        acc[i][j] = __builtin_amdgcn_mfma_f32_16x16x32_bf16(a1[i], b2[j], acc[i][j], 0, 0, 0);
#pragma unroll
    for (int i = 0; i < 4; i++)
#pragma unroll
      for (int j = 0; j < 4; j++)
        acc[i][j] = __builtin_amdgcn_mfma_f32_16x16x32_bf16(a2[i], b1[j], acc[i][j], 0, 0, 0);
  }

  // C/D layout (m89): col = lane&15, row = (lane>>4)*4 + reg
#pragma unroll
  for (int i = 0; i < 4; i++) {
#pragma unroll
    for (int j = 0; j < 4; j++) {
      const int gn = bx * 128 + 64 * wc + 16 * j + lm;
#pragma unroll
      for (int vv = 0; vv < 4; vv++) {
        const int gm = by * 128 + 64 * wr + 16 * i + 4 * lg + vv;
        const float y = acc[i][j][vv];
        if (MODE == 1) {
          Out[(size_t)gm * 2048 + gn] = y * 0.1f;
        } else {
          float r = __builtin_amdgcn_rcpf(y);
          r = fminf(fmaxf(r, -1.0f), 12.0f);
          const float jf = floorf(r);
          const float d0 = fmaf(jf, y, -1.0f);
          const float i0 = fminf(fmaxf(jf, 1.0f), 10.0f);
          const float i1 = fminf(fmaxf(jf + 1.0f, 1.0f), 10.0f);
          const float e0 = fmaf(i0, y, -1.0f);
          const float e1 = fmaf(i1, y, -1.0f);
          const float mind = fminf(fabsf(e0), fabsf(e1));
          const unsigned J = (unsigned)(int)((d0 >= 0.0f) ? jf : jf + 1.0f);
          MaskJ[(size_t)gm * 6144 + gn] = (unsigned char)((J <= 10u) ? J : 0u);
          if (mind < FLAG_EPS) {
            const unsigned idx = atomicAdd(cnt, 1u);
            if (idx < LIST_CAP) list[idx] = ((unsigned)gm << 13) | (unsigned)gn;
          }
        }
      }
    }
  }
}

// ---- transpose W -> WT f32 (rescue source; runs after gemm<0>, aliases Bpk)
__global__ __launch_bounds__(256) void transpose_w(
    const float* __restrict__ W0, const float* __restrict__ W1,
    const float* __restrict__ W2, float* __restrict__ WT) {
  __shared__ float tile[32][33];
  const int k0 = blockIdx.x * 32;
  const int c0 = blockIdx.y * 32;
  const int sel = c0 >> 11;
  const float* W = (sel == 0) ? W0 : ((sel == 1) ? W1 : W2);
  const int cc0 = c0 & 2047;
  const int tx = threadIdx.x, ty = threadIdx.y;  // (32,8)
#pragma unroll
  for (int rep = 0; rep < 4; rep++)
    tile[ty + 8 * rep][tx] = W[(size_t)(k0 + ty + 8 * rep) * 2048 + cc0 + tx];
  __syncthreads();
#pragma unroll
  for (int rep = 0; rep < 4; rep++)
    WT[(size_t)(c0 + ty + 8 * rep) * 2048 + k0 + tx] = tile[tx][ty + 8 * rep];
}

// ---- rescue: fp64 dot for flagged channels -> first-spike J (u8)
__global__ __launch_bounds__(256) void rescue(
    const float* __restrict__ X, const float* __restrict__ WT,
    const unsigned* __restrict__ list, const unsigned* __restrict__ cnt,
    unsigned char* __restrict__ MaskJ) {
  const unsigned nItems = min(*cnt, LIST_CAP);
  const unsigned gtid = blockIdx.x * blockDim.x + threadIdx.x;
  const unsigned wave = gtid >> 6, lane = gtid & 63;
  const unsigned nWaves = (gridDim.x * blockDim.x) >> 6;

  for (unsigned i = wave; i < nItems; i += nWaves) {
    const unsigned e = list[i];
    const int r = (int)(e >> 13), c = (int)(e & 8191u);
    const float* xrow = X + (size_t)((r < 2048) ? r : r - 2048) * 2048;
    const float sg = (r < 2048) ? 1.f : -1.f;
    const float* wrow = WT + (size_t)c * 2048;
    double s = 0.0;
#pragma unroll
    for (int it = 0; it < 8; it++) {
      const int k = (it * 64 + (int)lane) * 4;
      const float4 xv = *(const float4*)(xrow + k);
      const float4 wv = *(const float4*)(wrow + k);
      const float a0 = fmaxf(sg * xv.x, 0.f);
      const float a1 = fmaxf(sg * xv.y, 0.f);
      const float a2 = fmaxf(sg * xv.z, 0.f);
      const float a3 = fmaxf(sg * xv.w, 0.f);
      s += (double)a0 * (double)wv.x + (double)a1 * (double)wv.y +
           (double)a2 * (double)wv.z + (double)a3 * (double)wv.w;
    }
#pragma unroll
    for (int off = 32; off > 0; off >>= 1) s += __shfl_down(s, off);
    if (lane == 0) {
      double v = 0.0;
      unsigned J = 0;
#pragma unroll
      for (int t = 0; t < 10; t++) {
        v += s;
        if (J == 0u && v >= 1.0) J = (unsigned)(t + 1);
      }
      MaskJ[(size_t)r * 6144 + c] = (unsigned char)J;
    }
  }
}

// ---- spike_attn: per-token attention. QK via wave-ballot bitpack + popcount
// (exact integers, bit-identical to the float dot); PV float with xv in
// conflict-free [m][d] LDS; output transpose (d,h)->d*16+h.
__global__ __launch_bounds__(256) void spike_attn(const unsigned char* __restrict__ MaskJ,
                                                  float* __restrict__ xbar) {
  const int n = blockIdx.x;
  const int tid = threadIdx.x;
  const int lane = tid & 63;

  __shared__ unsigned long long qpB[16][2], qnB[16][2], kpB[16][2], knB[16][2];
  __shared__ float xvT[16 * 132];   // [m][d], stride 132 (conflict-free)
  __shared__ float attnS[16 * 17];  // [h][m], stride 17 (conflict-free)
  __shared__ unsigned lutS[16];

  if (tid < 16) lutS[tid] = d_LUT[tid];
  __syncthreads();

  const unsigned char* mp = MaskJ + (size_t)n * 6144;
  const unsigned char* mn = MaskJ + (size_t)(n + 2048) * 6144;

  unsigned q_p[8], q_n[8], k_p[8], k_n[8], v_p[8], v_n[8];
#pragma unroll
  for (int j = 0; j < 8; j++) {
    const int c = tid + 256 * j;
    q_p[j] = lutS[mp[c]];        q_n[j] = lutS[mn[c]];
    k_p[j] = lutS[mp[2048 + c]]; k_n[j] = lutS[mn[2048 + c]];
    v_p[j] = lutS[mp[4096 + c]]; v_n[j] = lutS[mn[4096 + c]];
  }

  float acc[8];
#pragma unroll
  for (int j = 0; j < 8; j++) acc[j] = 0.f;

  for (int t = 0; t < 10; t++) {
    // ---- bitpack spikes (ballot) + xv floats
#pragma unroll
    for (int j = 0; j < 8; j++) {
      const int c = tid + 256 * j;  // wave-uniform upper bits
      const unsigned long long bqp = __ballot((q_p[j] >> t) & 1u);
      const unsigned long long bqn = __ballot((q_n[j] >> t) & 1u);
      const unsigned long long bkp = __ballot((k_p[j] >> t) & 1u);
      const unsigned long long bkn = __ballot((k_n[j] >> t) & 1u);
      const int h = c >> 7, word = (c >> 6) & 1;
      if (lane == 0) {
        qpB[h][word] = bqp; qnB[h][word] = bqn;
        kpB[h][word] = bkp; knB[h][word] = bkn;
      }
      const int m = h, d = c & 127;
      xvT[m * 132 + d] =
          (float)((v_p[j] >> t) & 1u) - (float)((v_n[j] >> t) & 1u);
    }
    __syncthreads();

    // ---- attn[h][m] = 0.125 * popcount dot (exact)
    {
      const int h = tid >> 4, m = tid & 15;
      int dot = 0;
#pragma unroll
      for (int w = 0; w < 2; w++) {
        const unsigned long long qp = qpB[h][w], qn = qnB[h][w];
        const unsigned long long kp = kpB[m][w], kn = knB[m][w];
        dot += __popcll(qp & kp) + __popcll(qn & kn) -
               __popcll(qp & kn) - __popcll(qn & kp);
      }
      attnS[h * 17 + m] = (float)dot * 0.125f;
    }
    __syncthreads();

    // ---- PV: output o = d*16 + h; h = tid&15 constant across j
    {
      const int h = tid & 15;
      float arow[16];
#pragma unroll
      for (int m = 0; m < 16; m++) arow[m] = attnS[h * 17 + m];
#pragma unroll
      for (int j = 0; j < 8; j++) {
        const int d = (tid + 256 * j) >> 4;
        float s = 0.f;
#pragma unroll
        for (int m = 0; m < 16; m++) s += arow[m] * xvT[m * 132 + d];
        acc[j] += s;
      }
    }
    __syncthreads();
  }

#pragma unroll
  for (int j = 0; j < 8; j++) xbar[(size_t)n * 2048 + tid + 256 * j] = acc[j];
}

extern "C" void kernel_launch(void* const* d_in, const int* in_sizes, int n_in,
                              void* d_out, int out_size, void* d_ws, size_t ws_size,
                              hipStream_t stream) {
  const float* x = (const float*)d_in[0];
  // d_in[1] = freqs_cis (unused)
  const float* wq = (const float*)d_in[2];
  const float* wk = (const float*)d_in[3];
  const float* wv = (const float*)d_in[4];
  const float* wo = (const float*)d_in[5];
  float* out = (float*)d_out;

  char* ws = (char*)d_ws;
  unsigned char* MaskJ = (unsigned char*)ws;                       // 25.17 MB @0
  unsigned short* WOpk = (unsigned short*)ws;                      // 16.78 MB (MaskJ dead)
  char* reg2 = ws + (size_t)4096 * 6144;                           // @25.17 MB
  unsigned short* Bpk = (unsigned short*)reg2;                     // 50.33 MB
  float* WT = (float*)reg2;                                        // (Bpk dead)
  unsigned short* Xbpk = (unsigned short*)reg2;                    // 16.78 MB (WT dead)
  char* reg3 = reg2 + (size_t)6144 * 2048 * 2 * 2;                 // @75.50 MB
  unsigned short* Apk = (unsigned short*)reg3;                     // 33.55 MB
  float* xbar = (float*)reg3;                                      // 16.78 MB (Apk dead)
  unsigned* list = (unsigned*)(reg3 + (size_t)4096 * 2048 * 2 * 2);  // 2 MB @109.05
  unsigned* cnt = list + LIST_CAP;

  wsplit<1><<<dim3(48, 64), 256, 0, stream>>>(wq, wk, wv, Bpk, 48, cnt);
  asplit<1><<<dim3(32, 64), 256, 0, stream>>>(x, Apk, 32);
  // grid 1536 = 24 supertiles (6 in x) * 64
  gemm_dma<0><<<1536, 256, 0, stream>>>(Apk, Bpk, 32, 48, 6, MaskJ, list, cnt, nullptr);
  transpose_w<<<dim3(64, 192), dim3(32, 8), 0, stream>>>(wq, wk, wv, WT);
  rescue<<<2048, 256, 0, stream>>>(x, WT, list, cnt, MaskJ);
  spike_attn<<<2048, 256, 0, stream>>>(MaskJ, xbar);
  wsplit<0><<<dim3(16, 64), 256, 0, stream>>>(wo, wo, wo, WOpk, 16, nullptr);
  asplit<0><<<dim3(16, 64), 256, 0, stream>>>(xbar, Xbpk, 16);
  // grid 256 = 4 supertiles (2 in x) * 64
  gemm_dma<1><<<256, 256, 0, stream>>>(Xbpk, WOpk, 16, 16, 2, nullptr, nullptr, nullptr, out);
}

// Round 9
// 797.989 us; speedup vs baseline: 1.0625x; 1.0625x over previous
//
#include <hip/hip_runtime.h>
#include <hip/hip_bf16.h>

// Spiking attention, N=C=2048, T=10, heads=16, head_dim=128.
//
// Accuracy: spike decisions match an fp64 pipeline. Bulk GEMMs are bf16x2
// RNE-split MFMA (3 passes a1b1+a1b2+a2b1; sigma_dy ~ 3.5e-6). Closed-form IF
// epilogue certifies each channel (FLAG_EPS=4e-4 >= ~10 sigma of 10x-amplified
// dy) or flags it; flagged channels recomputed exactly in fp64 (rescue) ->
// masks bit-identical to fp64 pipeline regardless of MFMA shape/rounding.
// Constant input => IF spike train periodic, period J = first spike step;
// masks stored as J (u8); mask = LUT[J].
//
// R9 changes vs R8 (decision-invariant):
//  - gemm_dma: 32x32x16 MFMA (2382 vs 2075 TF ubench), 2 k-steps/iter with
//    per-k-step fragment loads (live frags 64->32 VGPR), and
//    __launch_bounds__(256,4) to force 4 blocks/CU -> cross-block overlap of
//    the DMA-drain barrier (the R6/R7/R8 475us flatline = occupancy-capped
//    latency hiding: MfmaUtil+VALUBusy 48% vs m98's 80%).
//  - grid back to plain (48,32): R8 swizzle raised FETCH, zero time delta.
//
// ws layout (111.2 MB):
//   @0        MaskJ u8 25.17 MB   | after spike_attn: WOpk 16.78 MB
//   @25.17M   Bpk 50.33 MB        | after gemm<0>: WT f32 50.33
//                                 | after rescue: Xbpk 16.78
//   @75.50M   Apk 33.55 MB        | after gemm<0>: xbar f32 16.78
//   @109.05M  list u32 512K = 2 MB, then cnt u32

#define LIST_CAP (512u * 1024u)
#define FLAG_EPS 4e-4f

typedef __attribute__((ext_vector_type(8))) short short8;
typedef __attribute__((ext_vector_type(16))) float floatx16;

__device__ const unsigned d_LUT[16] = {0u, 0x3FFu, 0x2AAu, 0x124u, 0x88u,
                                       0x210u, 0x20u, 0x40u, 0x80u, 0x100u,
                                       0x200u, 0u, 0u, 0u, 0u, 0u};

// RNE split f32 -> two bf16 planes (raw u16 in low half).
__device__ __forceinline__ void bf16x2_rne(float a, unsigned& p1, unsigned& p2) {
  const unsigned u = __float_as_uint(a);
  const unsigned t1 = u + 0x7FFFu + ((u >> 16) & 1u);
  p1 = t1 >> 16;
  const float r = a - __uint_as_float(t1 & 0xFFFF0000u);
  const unsigned u2 = __float_as_uint(r);
  p2 = (u2 + 0x7FFFu + ((u2 >> 16) & 1u)) >> 16;
}

// ---- wsplit: W columns -> packed swizzled plane-tile images (image row =
// W column). Image (plane,ct,k0i): row r at r*32 shorts, chunk c (8 shorts)
// at 8*(c ^ ((r>>1)&3)).
template <int ZERO_CNT>
__global__ __launch_bounds__(256) void wsplit(
    const float* __restrict__ W0, const float* __restrict__ W1,
    const float* __restrict__ W2, unsigned short* __restrict__ Bpk,
    int NCT, unsigned* __restrict__ cnt) {
  if (ZERO_CNT && blockIdx.x == 0 && blockIdx.y == 0 && threadIdx.x == 0)
    *cnt = 0u;
  __shared__ float Wf[32 * 132];
  const int ct = blockIdx.x, k0 = blockIdx.y * 32;
  const int c0 = ct * 128;
  const int sel = c0 >> 11;
  const float* W = (sel == 0) ? W0 : ((sel == 1) ? W1 : W2);
  const int cc0 = c0 & 2047;
  const int t = threadIdx.x;

  const int kr = t >> 3, cq = (t & 7) * 16;
#pragma unroll
  for (int u = 0; u < 4; u++) {
    const float4 v = *(const float4*)(W + (size_t)(k0 + kr) * 2048 + cc0 + cq + 4 * u);
    *(float4*)&Wf[kr * 132 + cq + 4 * u] = v;
  }
  __syncthreads();

  const int cc = t >> 1, ch0 = (t & 1) * 2;
  unsigned short* img1 = Bpk + ((size_t)(0 * NCT + ct) * 64 + blockIdx.y) * 4096;
  unsigned short* img2 = Bpk + ((size_t)(1 * NCT + ct) * 64 + blockIdx.y) * 4096;
#pragma unroll
  for (int c = ch0; c < ch0 + 2; c++) {
    unsigned q1[8], q2[8];
#pragma unroll
    for (int e = 0; e < 8; e++) bf16x2_rne(Wf[(c * 8 + e) * 132 + cc], q1[e], q2[e]);
    const int off = cc * 32 + 8 * (c ^ ((cc >> 1) & 3));
    uint4 P1, P2;
    P1.x = q1[0] | (q1[1] << 16); P1.y = q1[2] | (q1[3] << 16);
    P1.z = q1[4] | (q1[5] << 16); P1.w = q1[6] | (q1[7] << 16);
    P2.x = q2[0] | (q2[1] << 16); P2.y = q2[2] | (q2[3] << 16);
    P2.z = q2[4] | (q2[5] << 16); P2.w = q2[6] | (q2[7] << 16);
    *(uint4*)&img1[off] = P1;
    *(uint4*)&img2[off] = P2;
  }
}

// ---- asplit: row-major A (optionally relu(+-)) -> packed swizzled images.
template <int RELU>
__global__ __launch_bounds__(256) void asplit(
    const float* __restrict__ src, unsigned short* __restrict__ Apk, int NRT) {
  const int rt = blockIdx.x, k0i = blockIdx.y;
  const int t = threadIdx.x;
  const int r = t >> 1, half = t & 1;
  int grow = rt * 128 + r;
  float sgn = 1.f;
  if (RELU && grow >= 2048) { grow -= 2048; sgn = -1.f; }
  const float* s = src + (size_t)grow * 2048 + k0i * 32 + half * 16;
  float f[16];
#pragma unroll
  for (int u = 0; u < 4; u++) {
    const float4 v = *(const float4*)(s + 4 * u);
    f[4 * u + 0] = v.x; f[4 * u + 1] = v.y;
    f[4 * u + 2] = v.z; f[4 * u + 3] = v.w;
  }
  if (RELU) {
#pragma unroll
    for (int e = 0; e < 16; e++) f[e] = fmaxf(sgn * f[e], 0.f);
  }
  unsigned q1[16], q2[16];
#pragma unroll
  for (int e = 0; e < 16; e++) bf16x2_rne(f[e], q1[e], q2[e]);

  unsigned short* img1 = Apk + ((size_t)(0 * NRT + rt) * 64 + k0i) * 4096;
  unsigned short* img2 = Apk + ((size_t)(1 * NRT + rt) * 64 + k0i) * 4096;
#pragma unroll
  for (int cc = 0; cc < 2; cc++) {
    const int c = half * 2 + cc;
    const int off = r * 32 + 8 * (c ^ ((r >> 1) & 3));
    const int e0 = cc * 8;
    uint4 P1, P2;
    P1.x = q1[e0 + 0] | (q1[e0 + 1] << 16); P1.y = q1[e0 + 2] | (q1[e0 + 3] << 16);
    P1.z = q1[e0 + 4] | (q1[e0 + 5] << 16); P1.w = q1[e0 + 6] | (q1[e0 + 7] << 16);
    P2.x = q2[e0 + 0] | (q2[e0 + 1] << 16); P2.y = q2[e0 + 2] | (q2[e0 + 3] << 16);
    P2.z = q2[e0 + 4] | (q2[e0 + 5] << 16); P2.w = q2[e0 + 6] | (q2[e0 + 7] << 16);
    *(uint4*)&img1[off] = P1;
    *(uint4*)&img2[off] = P2;
  }
}

// ---- gemm_dma: pure-DMA bf16x2 MFMA GEMM, 128x128 tile, BK=32, 2x2 waves,
// 32x32x16 MFMA, 2 k-steps/iter with per-k-step fragment loads (32 live frag
// VGPRs), single 32 KB buffer, __launch_bounds__(256,4) for 4 blocks/CU.
// A/B frag layout (32x32x16): row = lane&31, k = (lane>>5)*8 + j.
// C/D layout (m74/m101): col = lane&31, row = (reg&3)+8*(reg>>2)+4*(lane>>5).
// MODE 0: closed-form IF -> MaskJ u8 + certify/flag. MODE 1: store y*0.1.
template <int MODE>
__global__ __launch_bounds__(256, 4) void gemm_dma(
    const unsigned short* __restrict__ Apk, const unsigned short* __restrict__ Bpk,
    int NRT, int NCT, unsigned char* __restrict__ MaskJ,
    unsigned* __restrict__ list, unsigned* __restrict__ cnt,
    float* __restrict__ Out) {
  __shared__ unsigned short sh[4][4096];  // A p1, A p2, B p1, B p2
  __shared__ unsigned lutS[16];

  const int tid = threadIdx.x;
  const int bx = blockIdx.x, by = blockIdx.y;
  const int lane = tid & 63, wave = tid >> 6;
  const int wr = wave >> 1, wc = wave & 1;
  const int lm = lane & 31, lg = lane >> 5;  // frag row / k-half

  if (MODE == 0 && tid < 16) lutS[tid] = d_LUT[tid];

  // each wave DMAs one 8 KB image per k-step
  const unsigned short* gsrc =
      (wave < 2) ? (Apk + ((size_t)(wave * NRT + by) * 64) * 4096)
                 : (Bpk + ((size_t)((wave - 2) * NCT + bx) * 64) * 4096);

  floatx16 acc[2][2];
#pragma unroll
  for (int i = 0; i < 2; i++)
#pragma unroll
    for (int j = 0; j < 2; j++)
#pragma unroll
      for (int e = 0; e < 16; e++) acc[i][j][e] = 0.f;

  for (int k0i = 0; k0i < 64; k0i++) {
    __syncthreads();  // prior iteration's fragment reads complete
    const unsigned short* gp = gsrc + (size_t)k0i * 4096;
#pragma unroll
    for (int i = 0; i < 8; i++) {
      __builtin_amdgcn_global_load_lds(
          (const __attribute__((address_space(1))) unsigned*)(gp + i * 512 + lane * 8),
          (__attribute__((address_space(3))) unsigned*)(&sh[wave][i * 512]), 16, 0, 0);
    }
    __syncthreads();  // drains vmcnt -> DMA landed

#pragma unroll
    for (int ks = 0; ks < 2; ks++) {
      const int ch = ks * 2 + lg;
      short8 a1[2], a2[2], b1[2], b2[2];
#pragma unroll
      for (int it = 0; it < 2; it++) {
        const int row = 64 * wr + 32 * it + lm;
        const int off = row * 32 + 8 * (ch ^ ((row >> 1) & 3));
        a1[it] = *(const short8*)&sh[0][off];
        a2[it] = *(const short8*)&sh[1][off];
      }
#pragma unroll
      for (int jt = 0; jt < 2; jt++) {
        const int row = 64 * wc + 32 * jt + lm;
        const int off = row * 32 + 8 * (ch ^ ((row >> 1) & 3));
        b1[jt] = *(const short8*)&sh[2][off];
        b2[jt] = *(const short8*)&sh[3][off];
      }
#pragma unroll
      for (int it = 0; it < 2; it++)
#pragma unroll
        for (int jt = 0; jt < 2; jt++)
          acc[it][jt] = __builtin_amdgcn_mfma_f32_32x32x16_bf16(
              a1[it], b1[jt], acc[it][jt], 0, 0, 0);
#pragma unroll
      for (int it = 0; it < 2; it++)
#pragma unroll
        for (int jt = 0; jt < 2; jt++)
          acc[it][jt] = __builtin_amdgcn_mfma_f32_32x32x16_bf16(
              a1[it], b2[jt], acc[it][jt], 0, 0, 0);
#pragma unroll
      for (int it = 0; it < 2; it++)
#pragma unroll
        for (int jt = 0; jt < 2; jt++)
          acc[it][jt] = __builtin_amdgcn_mfma_f32_32x32x16_bf16(
              a2[it], b1[jt], acc[it][jt], 0, 0, 0);
    }
  }

  // epilogue: C/D 32x32 layout
#pragma unroll
  for (int it = 0; it < 2; it++) {
#pragma unroll
    for (int jt = 0; jt < 2; jt++) {
      const int gn = bx * 128 + 64 * wc + 32 * jt + lm;
#pragma unroll
      for (int reg = 0; reg < 16; reg++) {
        const int gm = by * 128 + 64 * wr + 32 * it + (reg & 3) + 8 * (reg >> 2) + 4 * lg;
        const float y = acc[it][jt][reg];
        if (MODE == 1) {
          Out[(size_t)gm * 2048 + gn] = y * 0.1f;
        } else {
          float r = __builtin_amdgcn_rcpf(y);
          r = fminf(fmaxf(r, -1.0f), 12.0f);
          const float jf = floorf(r);
          const float d0 = fmaf(jf, y, -1.0f);
          const float i0 = fminf(fmaxf(jf, 1.0f), 10.0f);
          const float i1 = fminf(fmaxf(jf + 1.0f, 1.0f), 10.0f);
          const float e0 = fmaf(i0, y, -1.0f);
          const float e1 = fmaf(i1, y, -1.0f);
          const float mind = fminf(fabsf(e0), fabsf(e1));
          const unsigned J = (unsigned)(int)((d0 >= 0.0f) ? jf : jf + 1.0f);
          MaskJ[(size_t)gm * 6144 + gn] = (unsigned char)((J <= 10u) ? J : 0u);
          if (mind < FLAG_EPS) {
            const unsigned idx = atomicAdd(cnt, 1u);
            if (idx < LIST_CAP) list[idx] = ((unsigned)gm << 13) | (unsigned)gn;
          }
        }
      }
    }
  }
}

// ---- transpose W -> WT f32 (rescue source; runs after gemm<0>, aliases Bpk)
__global__ __launch_bounds__(256) void transpose_w(
    const float* __restrict__ W0, const float* __restrict__ W1,
    const float* __restrict__ W2, float* __restrict__ WT) {
  __shared__ float tile[32][33];
  const int k0 = blockIdx.x * 32;
  const int c0 = blockIdx.y * 32;
  const int sel = c0 >> 11;
  const float* W = (sel == 0) ? W0 : ((sel == 1) ? W1 : W2);
  const int cc0 = c0 & 2047;
  const int tx = threadIdx.x, ty = threadIdx.y;  // (32,8)
#pragma unroll
  for (int rep = 0; rep < 4; rep++)
    tile[ty + 8 * rep][tx] = W[(size_t)(k0 + ty + 8 * rep) * 2048 + cc0 + tx];
  __syncthreads();
#pragma unroll
  for (int rep = 0; rep < 4; rep++)
    WT[(size_t)(c0 + ty + 8 * rep) * 2048 + k0 + tx] = tile[tx][ty + 8 * rep];
}

// ---- rescue: fp64 dot for flagged channels -> first-spike J (u8)
__global__ __launch_bounds__(256) void rescue(
    const float* __restrict__ X, const float* __restrict__ WT,
    const unsigned* __restrict__ list, const unsigned* __restrict__ cnt,
    unsigned char* __restrict__ MaskJ) {
  const unsigned nItems = min(*cnt, LIST_CAP);
  const unsigned gtid = blockIdx.x * blockDim.x + threadIdx.x;
  const unsigned wave = gtid >> 6, lane = gtid & 63;
  const unsigned nWaves = (gridDim.x * blockDim.x) >> 6;

  for (unsigned i = wave; i < nItems; i += nWaves) {
    const unsigned e = list[i];
    const int r = (int)(e >> 13), c = (int)(e & 8191u);
    const float* xrow = X + (size_t)((r < 2048) ? r : r - 2048) * 2048;
    const float sg = (r < 2048) ? 1.f : -1.f;
    const float* wrow = WT + (size_t)c * 2048;
    double s = 0.0;
#pragma unroll
    for (int it = 0; it < 8; it++) {
      const int k = (it * 64 + (int)lane) * 4;
      const float4 xv = *(const float4*)(xrow + k);
      const float4 wv = *(const float4*)(wrow + k);
      const float a0 = fmaxf(sg * xv.x, 0.f);
      const float a1 = fmaxf(sg * xv.y, 0.f);
      const float a2 = fmaxf(sg * xv.z, 0.f);
      const float a3 = fmaxf(sg * xv.w, 0.f);
      s += (double)a0 * (double)wv.x + (double)a1 * (double)wv.y +
           (double)a2 * (double)wv.z + (double)a3 * (double)wv.w;
    }
#pragma unroll
    for (int off = 32; off > 0; off >>= 1) s += __shfl_down(s, off);
    if (lane == 0) {
      double v = 0.0;
      unsigned J = 0;
#pragma unroll
      for (int t = 0; t < 10; t++) {
        v += s;
        if (J == 0u && v >= 1.0) J = (unsigned)(t + 1);
      }
      MaskJ[(size_t)r * 6144 + c] = (unsigned char)J;
    }
  }
}

// ---- spike_attn: per-token attention. QK via wave-ballot bitpack + popcount
// (exact integers, bit-identical to the float dot); PV float with xv in
// conflict-free [m][d] LDS; output transpose (d,h)->d*16+h.
__global__ __launch_bounds__(256) void spike_attn(const unsigned char* __restrict__ MaskJ,
                                                  float* __restrict__ xbar) {
  const int n = blockIdx.x;
  const int tid = threadIdx.x;
  const int lane = tid & 63;

  __shared__ unsigned long long qpB[16][2], qnB[16][2], kpB[16][2], knB[16][2];
  __shared__ float xvT[16 * 132];   // [m][d], stride 132 (conflict-free)
  __shared__ float attnS[16 * 17];  // [h][m], stride 17 (conflict-free)
  __shared__ unsigned lutS[16];

  if (tid < 16) lutS[tid] = d_LUT[tid];
  __syncthreads();

  const unsigned char* mp = MaskJ + (size_t)n * 6144;
  const unsigned char* mn = MaskJ + (size_t)(n + 2048) * 6144;

  unsigned q_p[8], q_n[8], k_p[8], k_n[8], v_p[8], v_n[8];
#pragma unroll
  for (int j = 0; j < 8; j++) {
    const int c = tid + 256 * j;
    q_p[j] = lutS[mp[c]];        q_n[j] = lutS[mn[c]];
    k_p[j] = lutS[mp[2048 + c]]; k_n[j] = lutS[mn[2048 + c]];
    v_p[j] = lutS[mp[4096 + c]]; v_n[j] = lutS[mn[4096 + c]];
  }

  float acc[8];
#pragma unroll
  for (int j = 0; j < 8; j++) acc[j] = 0.f;

  for (int t = 0; t < 10; t++) {
    // ---- bitpack spikes (ballot) + xv floats
#pragma unroll
    for (int j = 0; j < 8; j++) {
      const int c = tid + 256 * j;  // wave-uniform upper bits
      const unsigned long long bqp = __ballot((q_p[j] >> t) & 1u);
      const unsigned long long bqn = __ballot((q_n[j] >> t) & 1u);
      const unsigned long long bkp = __ballot((k_p[j] >> t) & 1u);
      const unsigned long long bkn = __ballot((k_n[j] >> t) & 1u);
      const int h = c >> 7, word = (c >> 6) & 1;
      if (lane == 0) {
        qpB[h][word] = bqp; qnB[h][word] = bqn;
        kpB[h][word] = bkp; knB[h][word] = bkn;
      }
      const int m = h, d = c & 127;
      xvT[m * 132 + d] =
          (float)((v_p[j] >> t) & 1u) - (float)((v_n[j] >> t) & 1u);
    }
    __syncthreads();

    // ---- attn[h][m] = 0.125 * popcount dot (exact)
    {
      const int h = tid >> 4, m = tid & 15;
      int dot = 0;
#pragma unroll
      for (int w = 0; w < 2; w++) {
        const unsigned long long qp = qpB[h][w], qn = qnB[h][w];
        const unsigned long long kp = kpB[m][w], kn = knB[m][w];
        dot += __popcll(qp & kp) + __popcll(qn & kn) -
               __popcll(qp & kn) - __popcll(qn & kp);
      }
      attnS[h * 17 + m] = (float)dot * 0.125f;
    }
    __syncthreads();

    // ---- PV: output o = d*16 + h; h = tid&15 constant across j
    {
      const int h = tid & 15;
      float arow[16];
#pragma unroll
      for (int m = 0; m < 16; m++) arow[m] = attnS[h * 17 + m];
#pragma unroll
      for (int j = 0; j < 8; j++) {
        const int d = (tid + 256 * j) >> 4;
        float s = 0.f;
#pragma unroll
        for (int m = 0; m < 16; m++) s += arow[m] * xvT[m * 132 + d];
        acc[j] += s;
      }
    }
    __syncthreads();
  }

#pragma unroll
  for (int j = 0; j < 8; j++) xbar[(size_t)n * 2048 + tid + 256 * j] = acc[j];
}

extern "C" void kernel_launch(void* const* d_in, const int* in_sizes, int n_in,
                              void* d_out, int out_size, void* d_ws, size_t ws_size,
                              hipStream_t stream) {
  const float* x = (const float*)d_in[0];
  // d_in[1] = freqs_cis (unused)
  const float* wq = (const float*)d_in[2];
  const float* wk = (const float*)d_in[3];
  const float* wv = (const float*)d_in[4];
  const float* wo = (const float*)d_in[5];
  float* out = (float*)d_out;

  char* ws = (char*)d_ws;
  unsigned char* MaskJ = (unsigned char*)ws;                       // 25.17 MB @0
  unsigned short* WOpk = (unsigned short*)ws;                      // 16.78 MB (MaskJ dead)
  char* reg2 = ws + (size_t)4096 * 6144;                           // @25.17 MB
  unsigned short* Bpk = (unsigned short*)reg2;                     // 50.33 MB
  float* WT = (float*)reg2;                                        // (Bpk dead)
  unsigned short* Xbpk = (unsigned short*)reg2;                    // 16.78 MB (WT dead)
  char* reg3 = reg2 + (size_t)6144 * 2048 * 2 * 2;                 // @75.50 MB
  unsigned short* Apk = (unsigned short*)reg3;                     // 33.55 MB
  float* xbar = (float*)reg3;                                      // 16.78 MB (Apk dead)
  unsigned* list = (unsigned*)(reg3 + (size_t)4096 * 2048 * 2 * 2);  // 2 MB @109.05
  unsigned* cnt = list + LIST_CAP;

  wsplit<1><<<dim3(48, 64), 256, 0, stream>>>(wq, wk, wv, Bpk, 48, cnt);
  asplit<1><<<dim3(32, 64), 256, 0, stream>>>(x, Apk, 32);
  gemm_dma<0><<<dim3(48, 32), 256, 0, stream>>>(Apk, Bpk, 32, 48, MaskJ, list, cnt, nullptr);
  transpose_w<<<dim3(64, 192), dim3(32, 8), 0, stream>>>(wq, wk, wv, WT);
  rescue<<<2048, 256, 0, stream>>>(x, WT, list, cnt, MaskJ);
  spike_attn<<<2048, 256, 0, stream>>>(MaskJ, xbar);
  wsplit<0><<<dim3(16, 64), 256, 0, stream>>>(wo, wo, wo, WOpk, 16, nullptr);
  asplit<0><<<dim3(16, 64), 256, 0, stream>>>(xbar, Xbpk, 16);
  gemm_dma<1><<<dim3(16, 16), 256, 0, stream>>>(Xbpk, WOpk, 16, 16, nullptr, nullptr, nullptr, out);
}